// Round 1
// baseline (1144.552 us; speedup 1.0000x reference)
//
#include <hip/hip_runtime.h>

// GCN 2-layer forward, MI355X.
// Layer 1 reduced to scalar aggregation (x is [N,1]); layer 2 uses
// aggregate-then-matmul so the edge scatter is 64-wide.

__global__ void k_deg(const int* __restrict__ col, int* __restrict__ deg, int E) {
  int i = blockIdx.x * 256 + threadIdx.x;
  if (i < E) atomicAdd(&deg[col[i]], 1);
}

__global__ void k_dinv(const float* __restrict__ x, const int* __restrict__ deg,
                       float* __restrict__ dinv, float* __restrict__ t, int N) {
  int v = blockIdx.x * 256 + threadIdx.x;
  if (v < N) {
    float di = rsqrtf((float)(deg[v] + 1));  // +1 self-loop; deg>=1 always
    dinv[v] = di;
    t[v] = di * x[v];
  }
}

__global__ void k_scatter1(const int* __restrict__ row, const int* __restrict__ col,
                           const float* __restrict__ t, float* __restrict__ acc1, int E) {
  int i = blockIdx.x * 256 + threadIdx.x;
  if (i < E) atomicAdd(&acc1[col[i]], t[row[i]]);
}

__global__ void k_s(const float* __restrict__ t, const float* __restrict__ dinv,
                    float* __restrict__ acc1 /* in: edge sum, out: s */, int N) {
  int v = blockIdx.x * 256 + threadIdx.x;
  if (v < N) acc1[v] = dinv[v] * (acc1[v] + t[v]);  // s[v]
}

// One wave per edge; lane j handles feature j. g[u,j] recomputed from scalars
// (s[u], dinv[u]) -> 8B broadcast gather per edge instead of 256B.
__global__ void k_scatter2(const int* __restrict__ row, const int* __restrict__ col,
                           const float* __restrict__ s, const float* __restrict__ dinv,
                           const float* __restrict__ W1, const float* __restrict__ b1,
                           float* __restrict__ acc2, int E) {
  long gid = (long)blockIdx.x * 256 + threadIdx.x;
  int e = (int)(gid >> 6), j = (int)(gid & 63);
  if (e < E) {
    int u = row[e], v = col[e];
    float gu = dinv[u] * fmaxf(fmaf(W1[j], s[u], b1[j]), 0.0f);
    atomicAdd(&acc2[(long)v * 64 + j], gu);
  }
}

// One wave per node: finish aggregation (add self-loop term), 64x128 matmul
// against LDS-staged W2, then log_softmax over 128 via wave shuffles.
__global__ void k_out(const float* __restrict__ acc2, const float* __restrict__ s,
                      const float* __restrict__ dinv, const float* __restrict__ W1,
                      const float* __restrict__ b1, const float* __restrict__ W2,
                      const float* __restrict__ b2, float* __restrict__ out, int N) {
  __shared__ float sW[64 * 128];
  for (int i = threadIdx.x; i < 64 * 128; i += 256) sW[i] = W2[i];
  __syncthreads();
  int wave = threadIdx.x >> 6, lane = threadIdx.x & 63;
  int stride = gridDim.x * 4;
  float w1l = W1[lane], b1l = b1[lane];
  float zb0 = b2[lane], zb1 = b2[lane + 64];
  for (int v = blockIdx.x * 4 + wave; v < N; v += stride) {
    float di = dinv[v], sv = s[v];
    float gs = di * fmaxf(fmaf(w1l, sv, b1l), 0.0f);       // self-loop g[v,lane]
    float a = di * (acc2[(long)v * 64 + lane] + gs);       // agg[v,lane]
    float z0 = zb0, z1 = zb1;
#pragma unroll
    for (int j = 0; j < 64; ++j) {
      float aj = __shfl(a, j);                             // v_readlane (const j)
      z0 = fmaf(aj, sW[j * 128 + lane], z0);
      z1 = fmaf(aj, sW[j * 128 + lane + 64], z1);
    }
    // log_softmax over the 128 values held as (z0,z1) across 64 lanes
    float m = fmaxf(z0, z1);
#pragma unroll
    for (int off = 32; off; off >>= 1) m = fmaxf(m, __shfl_xor(m, off));
    float ssum = __expf(z0 - m) + __expf(z1 - m);
#pragma unroll
    for (int off = 32; off; off >>= 1) ssum += __shfl_xor(ssum, off);
    float l = __logf(ssum);
    out[(long)v * 128 + lane] = z0 - m - l;
    out[(long)v * 128 + lane + 64] = z1 - m - l;
  }
}

extern "C" void kernel_launch(void* const* d_in, const int* in_sizes, int n_in,
                              void* d_out, int out_size, void* d_ws, size_t ws_size,
                              hipStream_t stream) {
  const float* x  = (const float*)d_in[0];
  const int*  edge = (const int*)d_in[1];
  const float* W1 = (const float*)d_in[2];
  const float* b1 = (const float*)d_in[3];
  const float* W2 = (const float*)d_in[4];
  const float* b2 = (const float*)d_in[5];
  float* out = (float*)d_out;
  int N = in_sizes[0];
  int E = in_sizes[1] / 2;
  const int* row = edge;       // sources
  const int* col = edge + E;   // targets

  // ws layout: [deg N*4][acc1 N*4][acc2 N*256] (zeroed) [dinv N*4][t N*4]
  char* ws = (char*)d_ws;
  size_t zbytes = (size_t)N * (4 + 4 + 256);
  int*   deg  = (int*)ws;
  float* acc1 = (float*)(ws + (size_t)N * 4);
  float* acc2 = (float*)(ws + (size_t)N * 8);
  float* dinv = (float*)(ws + zbytes);
  float* t    = (float*)(ws + zbytes + (size_t)N * 4);

  hipMemsetAsync(ws, 0, zbytes, stream);
  k_deg<<<(E + 255) / 256, 256, 0, stream>>>(col, deg, E);
  k_dinv<<<(N + 255) / 256, 256, 0, stream>>>(x, deg, dinv, t, N);
  k_scatter1<<<(E + 255) / 256, 256, 0, stream>>>(row, col, t, acc1, E);
  k_s<<<(N + 255) / 256, 256, 0, stream>>>(t, dinv, acc1, N);
  long total2 = (long)E * 64;
  k_scatter2<<<(int)((total2 + 255) / 256), 256, 0, stream>>>(row, col, acc1, dinv, W1, b1, acc2, E);
  k_out<<<2048, 256, 0, stream>>>(acc2, acc1, dinv, W1, b1, W2, b2, out, N);
}

// Round 2
// 872.898 us; speedup vs baseline: 1.3112x; 1.3112x over previous
//
#include <hip/hip_runtime.h>

// GCN 2-layer forward, MI355X — gather formulation over on-device CSR.
// Layer 1 is scalar (x is [N,1]); layer 2 aggregates 64-wide via per-node
// gather with g[u,:] recomputed from 8B of per-node scalars, then fused
// 64x128 matmul + log_softmax.

__global__ void k_deg(const int* __restrict__ col, int* __restrict__ deg, int E) {
  int i = blockIdx.x * 256 + threadIdx.x;
  if (i < E) atomicAdd(&deg[col[i]], 1);
}

// 3-kernel exclusive scan of deg -> off
__global__ void k_scan1(const int* __restrict__ deg, int* __restrict__ off,
                        int* __restrict__ bsum, int N) {
  __shared__ int sh[256];
  int t = threadIdx.x;
  int i = blockIdx.x * 256 + t;
  int v = (i < N) ? deg[i] : 0;
  sh[t] = v;
  __syncthreads();
#pragma unroll
  for (int d = 1; d < 256; d <<= 1) {
    int add = (t >= d) ? sh[t - d] : 0;
    __syncthreads();
    sh[t] += add;
    __syncthreads();
  }
  if (i < N) off[i] = sh[t] - v;
  if (t == 255) bsum[blockIdx.x] = sh[255];
}

__global__ void k_scan2(int* __restrict__ bsum, int nb) {
  __shared__ int sh[512];
  int t = threadIdx.x;
  int v = (t < nb) ? bsum[t] : 0;
  sh[t] = v;
  __syncthreads();
#pragma unroll
  for (int d = 1; d < 512; d <<= 1) {
    int add = (t >= d) ? sh[t - d] : 0;
    __syncthreads();
    sh[t] += add;
    __syncthreads();
  }
  if (t < nb) bsum[t] = sh[t] - v;  // exclusive prefix of block sums
}

__global__ void k_scan3(int* __restrict__ off, const int* __restrict__ bsum, int N) {
  int i = blockIdx.x * 256 + threadIdx.x;
  if (i < N) off[i] += bsum[blockIdx.x];
}

__global__ void k_dinv(const float* __restrict__ x, const int* __restrict__ deg,
                       float* __restrict__ dinv, float* __restrict__ t, int N) {
  int v = blockIdx.x * 256 + threadIdx.x;
  if (v < N) {
    float di = rsqrtf((float)(deg[v] + 1));  // +1 self-loop
    dinv[v] = di;
    t[v] = di * x[v];
  }
}

__global__ void k_fill(const int* __restrict__ row, const int* __restrict__ col,
                       const int* __restrict__ off, int* __restrict__ cur,
                       int* __restrict__ nbr, int E) {
  int e = blockIdx.x * 256 + threadIdx.x;
  if (e < E) {
    int v = col[e];
    int p = atomicAdd(&cur[v], 1);
    nbr[off[v] + p] = row[e];
  }
}

// s[v] = dinv[v] * (sum_{u->v} t[u] + t[v]); pack (s, dinv) for layer 2.
__global__ void k_gather1(const int* __restrict__ off, const int* __restrict__ deg,
                          const int* __restrict__ nbr, const float* __restrict__ t,
                          const float* __restrict__ dinv, float2* __restrict__ sd, int N) {
  int v = blockIdx.x * 256 + threadIdx.x;
  if (v >= N) return;
  int st = off[v], d = deg[v];
  float sum = t[v];
  for (int k = 0; k < d; ++k) sum += t[nbr[st + k]];
  float di = dinv[v];
  sd[v] = make_float2(di * sum, di);
}

// One wave per node: gather-aggregate layer-2 input, 64x128 matmul vs
// LDS-staged W2 (float2-packed, conflict-free), log_softmax, store.
__global__ void __launch_bounds__(256) k_fused(
    const int* __restrict__ off, const int* __restrict__ deg,
    const int* __restrict__ nbr, const float2* __restrict__ sd,
    const float* __restrict__ W1, const float* __restrict__ b1,
    const float* __restrict__ W2, const float* __restrict__ b2,
    float* __restrict__ out, int N) {
  __shared__ float2 sW[64 * 64];  // sW[j*64+l] = (W2[j,l], W2[j,l+64])
  for (int i = threadIdx.x; i < 4096; i += 256) {
    int j = i >> 6, l = i & 63;
    sW[i] = make_float2(W2[j * 128 + l], W2[j * 128 + 64 + l]);
  }
  __syncthreads();
  int wave = threadIdx.x >> 6, lane = threadIdx.x & 63;
  float w1l = W1[lane], b1l = b1[lane];
  float zb0 = b2[lane], zb1 = b2[lane + 64];
  int stride = gridDim.x * 4;
  for (int v = blockIdx.x * 4 + wave; v < N; v += stride) {
    float2 sv = sd[v];
    float a = sv.y * fmaxf(fmaf(w1l, sv.x, b1l), 0.0f);  // self-loop term
    int st = off[v], d = deg[v];
    for (int k = 0; k < d; ++k) {
      float2 su = sd[nbr[st + k]];  // broadcast loads (8B, L2-resident)
      a += su.y * fmaxf(fmaf(w1l, su.x, b1l), 0.0f);
    }
    a *= sv.y;
    float z0 = zb0, z1 = zb1;
#pragma unroll
    for (int j = 0; j < 64; ++j) {
      float aj = __shfl(a, j);        // readlane broadcast (const j)
      float2 w = sW[j * 64 + lane];   // ds_read_b64, 2-way aliasing = free
      z0 = fmaf(aj, w.x, z0);
      z1 = fmaf(aj, w.y, z1);
    }
    // log_softmax over 128 logits held as (z0,z1) across 64 lanes
    float m = fmaxf(z0, z1);
#pragma unroll
    for (int o = 32; o; o >>= 1) m = fmaxf(m, __shfl_xor(m, o));
    float ssum = __expf(z0 - m) + __expf(z1 - m);
#pragma unroll
    for (int o = 32; o; o >>= 1) ssum += __shfl_xor(ssum, o);
    float l = __logf(ssum);
    long base = (long)v * 128;
    out[base + lane] = z0 - m - l;
    out[base + 64 + lane] = z1 - m - l;
  }
}

extern "C" void kernel_launch(void* const* d_in, const int* in_sizes, int n_in,
                              void* d_out, int out_size, void* d_ws, size_t ws_size,
                              hipStream_t stream) {
  const float* x  = (const float*)d_in[0];
  const int* edge = (const int*)d_in[1];
  const float* W1 = (const float*)d_in[2];
  const float* b1 = (const float*)d_in[3];
  const float* W2 = (const float*)d_in[4];
  const float* b2 = (const float*)d_in[5];
  float* out = (float*)d_out;
  int N = in_sizes[0];
  int E = in_sizes[1] / 2;
  const int* row = edge;      // sources
  const int* col = edge + E;  // targets
  int nbN = (N + 255) / 256;
  int nbE = (E + 255) / 256;

  // ws layout: [deg N][cur N] (zeroed) [off N][bsum 512][t N][dinv N][sd 2N][nbr E]
  char* ws = (char*)d_ws;
  int*   deg  = (int*)ws;
  int*   cur  = (int*)(ws + (size_t)N * 4);
  int*   off  = (int*)(ws + (size_t)N * 8);
  int*   bsum = (int*)(ws + (size_t)N * 12);
  float* t    = (float*)(ws + (size_t)N * 12 + 2048);
  float* dinv = (float*)(ws + (size_t)N * 16 + 2048);
  float2* sd  = (float2*)(ws + (size_t)N * 20 + 2048);
  int*   nbr  = (int*)(ws + (size_t)N * 28 + 2048);

  hipMemsetAsync(ws, 0, (size_t)N * 8, stream);  // deg + cur
  k_deg<<<nbE, 256, 0, stream>>>(col, deg, E);
  k_scan1<<<nbN, 256, 0, stream>>>(deg, off, bsum, N);
  k_scan2<<<1, 512, 0, stream>>>(bsum, nbN);
  k_scan3<<<nbN, 256, 0, stream>>>(off, bsum, N);
  k_dinv<<<nbN, 256, 0, stream>>>(x, deg, dinv, t, N);
  k_fill<<<nbE, 256, 0, stream>>>(row, col, off, cur, nbr, E);
  k_gather1<<<nbN, 256, 0, stream>>>(off, deg, nbr, t, dinv, sd, N);
  k_fused<<<1024, 256, 0, stream>>>(off, deg, nbr, sd, W1, b1, W2, b2, out, N);
}

// Round 3
// 546.670 us; speedup vs baseline: 2.0937x; 1.5968x over previous
//
#include <hip/hip_runtime.h>

// GCN 2-layer forward, MI355X — gather formulation over on-device CSR.
// Layer 2 aggregation is lane-parallel: 64 neighbors gathered per wave-step,
// staged in LDS, then broadcast-consumed (uniform-address ds_read) so no
// serial dependent-load chain remains.

__global__ void k_deg(const int* __restrict__ col, int* __restrict__ deg, int E) {
  int i = blockIdx.x * 256 + threadIdx.x;
  if (i < E) atomicAdd(&deg[col[i]], 1);
}

// exclusive scan of deg -> off (3 kernels); also computes dinv, t (fused).
__global__ void k_scan1(const int* __restrict__ deg, int* __restrict__ off,
                        int* __restrict__ bsum, const float* __restrict__ x,
                        float* __restrict__ dinv, float* __restrict__ t, int N) {
  __shared__ int sh[256];
  int tt = threadIdx.x;
  int i = blockIdx.x * 256 + tt;
  int v = (i < N) ? deg[i] : 0;
  sh[tt] = v;
  __syncthreads();
#pragma unroll
  for (int d = 1; d < 256; d <<= 1) {
    int add = (tt >= d) ? sh[tt - d] : 0;
    __syncthreads();
    sh[tt] += add;
    __syncthreads();
  }
  if (i < N) {
    off[i] = sh[tt] - v;
    float di = rsqrtf((float)(v + 1));  // +1 self-loop
    dinv[i] = di;
    t[i] = di * x[i];
  }
  if (tt == 255) bsum[blockIdx.x] = sh[255];
}

__global__ void k_scan2(int* __restrict__ bsum, int nb) {
  __shared__ int sh[512];
  int t = threadIdx.x;
  int v = (t < nb) ? bsum[t] : 0;
  sh[t] = v;
  __syncthreads();
#pragma unroll
  for (int d = 1; d < 512; d <<= 1) {
    int add = (t >= d) ? sh[t - d] : 0;
    __syncthreads();
    sh[t] += add;
    __syncthreads();
  }
  if (t < nb) bsum[t] = sh[t] - v;
}

__global__ void k_scan3(int* __restrict__ off, const int* __restrict__ bsum, int N) {
  int i = blockIdx.x * 256 + threadIdx.x;
  if (i < N) off[i] += bsum[blockIdx.x];
}

__global__ void k_fill(const int* __restrict__ row, const int* __restrict__ col,
                       const int* __restrict__ off, int* __restrict__ cur,
                       int* __restrict__ nbr, int E) {
  int e = blockIdx.x * 256 + threadIdx.x;
  if (e < E) {
    int v = col[e];
    int p = atomicAdd(&cur[v], 1);
    nbr[off[v] + p] = row[e];
  }
}

// s[v] = dinv[v]*(sum t[u] + t[v]); wave per node, lane-parallel gather.
__global__ void k_gather1(const int* __restrict__ off, const int* __restrict__ deg,
                          const int* __restrict__ nbr, const float* __restrict__ t,
                          const float* __restrict__ dinv, float2* __restrict__ sd, int N) {
  int wave = threadIdx.x >> 6, lane = threadIdx.x & 63;
  int v = blockIdx.x * 4 + wave;
  if (v >= N) return;
  int st = off[v], d = deg[v];
  float sum = 0.0f;
  for (int base = 0; base < d; base += 64) {
    float val = 0.0f;
    if (base + lane < d) val = t[nbr[st + base + lane]];
    sum += val;
  }
#pragma unroll
  for (int o = 32; o; o >>= 1) sum += __shfl_xor(sum, o);
  if (lane == 0) {
    float di = dinv[v];
    sd[v] = make_float2(di * (sum + t[v]), di);
  }
}

// One wave per node: lane-parallel gather of neighbor scalars -> LDS ->
// broadcast-consume; then 64x128 matmul vs LDS W2 + log_softmax.
__global__ void __launch_bounds__(256) k_fused(
    const int* __restrict__ off, const int* __restrict__ deg,
    const int* __restrict__ nbr, const float2* __restrict__ sd,
    const float* __restrict__ W1, const float* __restrict__ b1,
    const float* __restrict__ W2, const float* __restrict__ b2,
    float* __restrict__ out, int N) {
  __shared__ float2 sW[64 * 64];     // sW[j*64+l] = (W2[j,l], W2[j,l+64])
  __shared__ float2 sbuf[4][64];     // per-wave neighbor-scalar staging
  for (int i = threadIdx.x; i < 4096; i += 256) {
    int j = i >> 6, l = i & 63;
    sW[i] = make_float2(W2[j * 128 + l], W2[j * 128 + 64 + l]);
  }
  __syncthreads();
  int wave = threadIdx.x >> 6, lane = threadIdx.x & 63;
  float w1l = W1[lane], b1l = b1[lane];
  float zb0 = b2[lane], zb1 = b2[lane + 64];
  int stride = gridDim.x * 4;
  for (int v = blockIdx.x * 4 + wave; v < N; v += stride) {
    float2 sv = sd[v];
    float a = sv.y * fmaxf(fmaf(w1l, sv.x, b1l), 0.0f);  // self-loop g[v,lane]
    int st = off[v], d = deg[v];
    for (int base = 0; base < d; base += 64) {
      int cnt = min(64, d - base);
      float2 su = make_float2(0.0f, 0.0f);
      if (lane < cnt) su = sd[nbr[st + base + lane]];  // parallel random 8B (L2)
      sbuf[wave][lane] = su;
#pragma unroll 4
      for (int k = 0; k < cnt; ++k) {
        float2 w = sbuf[wave][k];  // uniform address -> broadcast, no conflict
        a += w.y * fmaxf(fmaf(w1l, w.x, b1l), 0.0f);
      }
    }
    a *= sv.y;
    float z0 = zb0, z1 = zb1;
#pragma unroll
    for (int j = 0; j < 64; ++j) {
      float aj = __shfl(a, j);       // readlane (const j)
      float2 w = sW[j * 64 + lane];  // ds_read_b64, 2-way aliasing = free
      z0 = fmaf(aj, w.x, z0);
      z1 = fmaf(aj, w.y, z1);
    }
    float m = fmaxf(z0, z1);
#pragma unroll
    for (int o = 32; o; o >>= 1) m = fmaxf(m, __shfl_xor(m, o));
    float ssum = __expf(z0 - m) + __expf(z1 - m);
#pragma unroll
    for (int o = 32; o; o >>= 1) ssum += __shfl_xor(ssum, o);
    float l = __logf(ssum);
    long base = (long)v * 128;
    out[base + lane] = z0 - m - l;
    out[base + 64 + lane] = z1 - m - l;
  }
}

extern "C" void kernel_launch(void* const* d_in, const int* in_sizes, int n_in,
                              void* d_out, int out_size, void* d_ws, size_t ws_size,
                              hipStream_t stream) {
  const float* x  = (const float*)d_in[0];
  const int* edge = (const int*)d_in[1];
  const float* W1 = (const float*)d_in[2];
  const float* b1 = (const float*)d_in[3];
  const float* W2 = (const float*)d_in[4];
  const float* b2 = (const float*)d_in[5];
  float* out = (float*)d_out;
  int N = in_sizes[0];
  int E = in_sizes[1] / 2;
  const int* row = edge;      // sources
  const int* col = edge + E;  // targets
  int nbN = (N + 255) / 256;
  int nbE = (E + 255) / 256;

  // ws layout: [deg N][cur N] (zeroed) [off N][bsum 512][t N][dinv N][sd 2N][nbr E]
  char* ws = (char*)d_ws;
  int*   deg  = (int*)ws;
  int*   cur  = (int*)(ws + (size_t)N * 4);
  int*   off  = (int*)(ws + (size_t)N * 8);
  int*   bsum = (int*)(ws + (size_t)N * 12);
  float* t    = (float*)(ws + (size_t)N * 12 + 2048);
  float* dinv = (float*)(ws + (size_t)N * 16 + 2048);
  float2* sd  = (float2*)(ws + (size_t)N * 20 + 2048);
  int*   nbr  = (int*)(ws + (size_t)N * 28 + 2048);

  hipMemsetAsync(ws, 0, (size_t)N * 8, stream);  // deg + cur
  k_deg<<<nbE, 256, 0, stream>>>(col, deg, E);
  k_scan1<<<nbN, 256, 0, stream>>>(deg, off, bsum, x, dinv, t, N);
  k_scan2<<<1, 512, 0, stream>>>(bsum, nbN);
  k_scan3<<<nbN, 256, 0, stream>>>(off, bsum, N);
  k_fill<<<nbE, 256, 0, stream>>>(row, col, off, cur, nbr, E);
  k_gather1<<<(N + 3) / 4, 256, 0, stream>>>(off, deg, nbr, t, dinv, sd, N);
  k_fused<<<1024, 256, 0, stream>>>(off, deg, nbr, sd, W1, b1, W2, b2, out, N);
}